// Round 10
// baseline (96.494 us; speedup 1.0000x reference)
//
#include <hip/hip_runtime.h>

// out[b] = sum_h [ dot(x1_bh,W1_h) + b1_h + dot(x2_bh,W2_h)
//                  + sum_o x2_bh[o] * dot(W3_h[o,:], x1_bh) ]
// B=16384, HEAD=8, DIM=128.
//
// R10 (from R9 post-mortem: time is flat vs HBM traffic -> structural
// serialization, not memory). Changes:
//  - Stage ALL 64 KB of W3_h once per block (single-buffered LDS), then a
//    RUNTIME-bound mt loop (loop count is a kernel arg -> no unroll -> no
//    R6-style acc spill) processes 4 m-tiles per block. Staging amortized 4x.
//  - ZERO barriers in the main loop: after the one post-staging
//    __syncthreads, LDS is read-only; waves drift and self-overlap.
//  - Grid 512 blocks (64 per head x 8 heads) = 2 blocks/CU (LDS-limited) =
//    ONE generation. head = bid&7 keeps per-head W3 XCD-pinned.
//  - Per mt-iteration: 32 x2 epilogue loads issued at the top (in flight
//    under all 4 kk phases), x1 rolling-prefetched one kk ahead.
//  - Numerics unchanged (proven R5-R9): split-bf16 3-pass, fragment-ordered
//    pre-split W3, barrier-free shuffle epilogue, psum + reduce kernel.
// Fragment layouts (verified m89/m91): A: m=lane&15, k=(lane>>4)*8+j;
//   B: n=lane&15, same k; C/D: col=lane&15, row=(lane>>4)*4+reg.
// ws: [0,256K) whi | [256K,512K) wlo | [512K,1M) psum float[8][16384]

#define NB 16384
#define NHEAD 8
#define NDIM 128
#define MT 4                    // m-tiles per block (runtime arg defeats unroll)

typedef __attribute__((ext_vector_type(8))) short bf16x8;
typedef __attribute__((ext_vector_type(4))) float f32x4;

__device__ __forceinline__ void gload_lds16(const void* g, void* l) {
    __builtin_amdgcn_global_load_lds(
        (const __attribute__((address_space(1))) unsigned*)g,
        (__attribute__((address_space(3))) unsigned*)l, 16, 0, 0);
}

// ---- prep: split W3 into bf16 hi/lo in MFMA B-fragment order ----
// t = ((h*4+kk)*8+nt)*64+lane ; writes whi[t*8..t*8+8)
__global__ __launch_bounds__(256) void prep_w3(
    const float* __restrict__ W3, short* __restrict__ whi,
    short* __restrict__ wlo)
{
    const int t    = blockIdx.x * 256 + threadIdx.x;   // 16384 threads
    const int lane = t & 63;
    const int nt   = (t >> 6) & 7;
    const int kk   = (t >> 9) & 3;
    const int h    = t >> 11;
    const int lm   = lane & 15;
    const int lg   = lane >> 4;

    const float* src = W3 + ((size_t)(h * NDIM + nt * 16 + lm)) * NDIM
                          + kk * 32 + lg * 8;
    const float4 a = *reinterpret_cast<const float4*>(src);
    const float4 b = *reinterpret_cast<const float4*>(src + 4);
    float xf[8] = {a.x, a.y, a.z, a.w, b.x, b.y, b.z, b.w};
    bf16x8 hi, lo;
#pragma unroll
    for (int j = 0; j < 8; ++j) {
        const unsigned u = __float_as_uint(xf[j]);
        hi[j] = (short)(u >> 16);
        const float hf = __uint_as_float(u & 0xffff0000u);
        lo[j] = (short)(__float_as_uint(xf[j] - hf) >> 16);
    }
    reinterpret_cast<bf16x8*>(whi)[t] = hi;
    reinterpret_cast<bf16x8*>(wlo)[t] = lo;
}

// ---- main: head = bid&7, 4 waves, MT m-tiles of 64 samples per block ----
__global__ __launch_bounds__(256, 2) void bilinear_mfma(
    const float* __restrict__ x1, const float* __restrict__ x2,
    const float* __restrict__ W1, const float* __restrict__ W2,
    const short* __restrict__ whi, const short* __restrict__ wlo,
    float* __restrict__ psum, int mtCount)
{
    const int tid = threadIdx.x;
    const int w   = tid >> 6;
    const int l   = tid & 63;
    const int lm  = l & 15;
    const int lg  = l >> 4;
    const int bid = blockIdx.x;
    const int h   = bid & 7;               // head pinned per-XCD (round-robin)
    const int bt0 = (bid >> 3) * (64 * MT);

    __shared__ short lhi[4][4096];         // 32 KB: all 4 kk slabs, frag order
    __shared__ short llo[4][4096];         // 32 KB

    const short* __restrict__ shi = whi + (size_t)h * 16384;
    const short* __restrict__ slo = wlo + (size_t)h * 16384;
    const float* __restrict__ w1base = W1 + h * NDIM;

    // ---- stage the whole 64 KB once: 8+8 gload_lds16 per thread ----
#pragma unroll
    for (int i = 0; i < 8; ++i) {
        gload_lds16(shi + (size_t)(i * 256 + tid) * 8,
                    &lhi[0][0] + (size_t)(i * 256 + w * 64) * 8);
        gload_lds16(slo + (size_t)(i * 256 + tid) * 8,
                    &llo[0][0] + (size_t)(i * 256 + w * 64) * 8);
    }

    float w2v[8];
#pragma unroll
    for (int nt = 0; nt < 8; ++nt) w2v[nt] = W2[h * NDIM + nt * 16 + lm];

    __syncthreads();   // drains vmcnt; the ONLY barrier in this kernel

    for (int mt = 0; mt < mtCount; ++mt) {   // runtime bound -> no unroll
        const int bw = bt0 + mt * 64 + w * 16;

        // x2 epilogue loads issued first: in flight under all 4 kk phases
        float x2r[4][8];
        {
            const float* x2base = x2 + (size_t)(bw + lg * 4) * (NHEAD * NDIM)
                                     + h * NDIM + lm;
#pragma unroll
            for (int r = 0; r < 4; ++r)
#pragma unroll
                for (int nt = 0; nt < 8; ++nt)
                    x2r[r][nt] = x2base[(size_t)r * (NHEAD * NDIM) + nt * 16];
        }

        const float* x1base = x1 + (size_t)(bw + lm) * (NHEAD * NDIM)
                                 + h * NDIM + lg * 8;
        float4 pa = *reinterpret_cast<const float4*>(x1base);
        float4 pb = *reinterpret_cast<const float4*>(x1base + 4);

        f32x4 acc[8];
#pragma unroll
        for (int nt = 0; nt < 8; ++nt) acc[nt] = (f32x4)0.f;
        float t1 = 0.f;

#pragma unroll
        for (int kk = 0; kk < 4; ++kk) {
            const float4 ca = pa, cb = pb;
            if (kk < 3) {   // rolling x1 prefetch one kk ahead
                pa = *reinterpret_cast<const float4*>(x1base + (kk + 1) * 32);
                pb = *reinterpret_cast<const float4*>(x1base + (kk + 1) * 32 + 4);
            }

            // A-fragment split + t1 from exact fp32 values
            bf16x8 ahi, alo;
            {
                const int k0 = kk * 32 + lg * 8;
                const float4 wa = *reinterpret_cast<const float4*>(w1base + k0);
                const float4 wb = *reinterpret_cast<const float4*>(w1base + k0 + 4);
                float xf[8]  = {ca.x, ca.y, ca.z, ca.w, cb.x, cb.y, cb.z, cb.w};
                float w1f[8] = {wa.x, wa.y, wa.z, wa.w, wb.x, wb.y, wb.z, wb.w};
#pragma unroll
                for (int j = 0; j < 8; ++j) {
                    const unsigned u = __float_as_uint(xf[j]);
                    ahi[j] = (short)(u >> 16);
                    const float hf = __uint_as_float(u & 0xffff0000u);
                    alo[j] = (short)(__float_as_uint(xf[j] - hf) >> 16);
                    t1 += xf[j] * w1f[j];
                }
            }

            // B-fragments from LDS (linear ds_read_b128, conflict-free)
#pragma unroll
            for (int nt = 0; nt < 8; ++nt) {
                const bf16x8 bhi = *reinterpret_cast<const bf16x8*>(
                    &lhi[kk][nt * 512 + l * 8]);
                const bf16x8 blo = *reinterpret_cast<const bf16x8*>(
                    &llo[kk][nt * 512 + l * 8]);
                acc[nt] = __builtin_amdgcn_mfma_f32_16x16x32_bf16(ahi, bhi, acc[nt], 0, 0, 0);
                acc[nt] = __builtin_amdgcn_mfma_f32_16x16x32_bf16(alo, bhi, acc[nt], 0, 0, 0);
                acc[nt] = __builtin_amdgcn_mfma_f32_16x16x32_bf16(ahi, blo, acc[nt], 0, 0, 0);
            }
        }

        // ---- barrier-free epilogue: sum_o (P+W2[o])*x2[b,o], fold t1 ----
        float cr[4];
#pragma unroll
        for (int r = 0; r < 4; ++r) {
            float s = 0.f;
#pragma unroll
            for (int nt = 0; nt < 8; ++nt)
                s += (acc[nt][r] + w2v[nt]) * x2r[r][nt];
            cr[r] = s;
        }
#pragma unroll
        for (int m = 1; m < 16; m <<= 1)
#pragma unroll
            for (int r = 0; r < 4; ++r) cr[r] += __shfl_xor(cr[r], m, 64);

        // t1: sum over lg groups -> every lane holds T(bw + (l&15))
        float tf = t1;
        tf += __shfl_xor(tf, 16, 64);
        tf += __shfl_xor(tf, 32, 64);
#pragma unroll
        for (int r = 0; r < 4; ++r) cr[r] += __shfl(tf, lg * 4 + r, 64);

        if (lm == 0) {
            float4 st;
            st.x = cr[0]; st.y = cr[1]; st.z = cr[2]; st.w = cr[3];
            *reinterpret_cast<float4*>(&psum[(size_t)h * NB + bw + lg * 4]) = st;
        }
    }
}

__global__ __launch_bounds__(256) void bilinear_reduce(
    const float* __restrict__ psum, const float* __restrict__ b1,
    float* __restrict__ out)
{
    const int i = blockIdx.x * 256 + threadIdx.x;
    float bs = 0.f;
#pragma unroll
    for (int hh = 0; hh < NHEAD; ++hh) bs += b1[hh];
    float s = bs;
#pragma unroll
    for (int hh = 0; hh < NHEAD; ++hh) s += psum[(size_t)hh * NB + i];
    out[i] = s;
}

extern "C" void kernel_launch(void* const* d_in, const int* in_sizes, int n_in,
                              void* d_out, int out_size, void* d_ws, size_t ws_size,
                              hipStream_t stream) {
    const float* x1 = (const float*)d_in[0];
    const float* x2 = (const float*)d_in[1];
    const float* W1 = (const float*)d_in[2];
    const float* b1 = (const float*)d_in[3];
    const float* W2 = (const float*)d_in[4];
    const float* W3 = (const float*)d_in[5];
    float* out = (float*)d_out;

    short* whi = (short*)d_ws;                          // 256 KB
    short* wlo = whi + (size_t)NHEAD * NDIM * NDIM;     // 256 KB
    float* psum = (float*)((char*)d_ws + 512 * 1024);   // 512 KB

    prep_w3<<<dim3(64), dim3(256), 0, stream>>>(W3, whi, wlo);
    bilinear_mfma<<<dim3(NB / (64 * MT) * NHEAD), dim3(256), 0, stream>>>(
        x1, x2, W1, W2, whi, wlo, psum, MT);
    bilinear_reduce<<<dim3(NB / 256), dim3(256), 0, stream>>>(psum, b1, out);
}

// Round 11
// 94.088 us; speedup vs baseline: 1.0256x; 1.0256x over previous
//
#include <hip/hip_runtime.h>

// out[b] = sum_h [ dot(x1_bh,W1_h) + b1_h + dot(x2_bh,W2_h)
//                  + sum_o x2_bh[o] * dot(W3_h[o,:], x1_bh) ]
// B=16384, HEAD=8, DIM=128.
//
// R11: barrier-free main loop (no vmcnt-drain stalls: __syncthreads on CDNA
// drains ALL in-flight loads, which silently serialized R7-R9's "pipelines")
// + B-fragment reuse across 2 m-tiles (halves LDS ds_read pressure, which at
// 1 tile exceeded MFMA pipe time 768 vs 466 cyc).
//  - Stage all 64 KB of W3_h once per block (gload_lds16, zero reg cost),
//    ONE __syncthreads, then runtime-bound it-loop (no unroll -> no spill).
//  - Per it: 2 m-tiles with NAMED acc0[8]/acc1[8]; per (kk,nt) one bhi/blo
//    ds_read pair feeds 6 MFMAs. x2 only in the per-tile epilogue (32
//    independent dwords -> natural MLP, no sustained registers).
//  - launch_bounds(256,2): 256-reg budget, est. peak ~150 live, no cliff.
//  - Grid 512 = 2 blocks/CU = ONE generation; head=bid&7 XCD-pins W3.
//  - Numerics unchanged (proven R5-R10): split-bf16 3-pass, fragment-ordered
//    pre-split W3, shuffle epilogue, psum + reduce kernel.
// Fragment layouts (verified m89/m91): A: m=lane&15, k=(lane>>4)*8+j;
//   B: n=lane&15, same k; C/D: col=lane&15, row=(lane>>4)*4+reg.
// ws: [0,256K) whi | [256K,512K) wlo | [512K,1M) psum float[8][16384]

#define NB 16384
#define NHEAD 8
#define NDIM 128

typedef __attribute__((ext_vector_type(8))) short bf16x8;
typedef __attribute__((ext_vector_type(4))) float f32x4;

__device__ __forceinline__ void gload_lds16(const void* g, void* l) {
    __builtin_amdgcn_global_load_lds(
        (const __attribute__((address_space(1))) unsigned*)g,
        (__attribute__((address_space(3))) unsigned*)l, 16, 0, 0);
}

// ---- prep: split W3 into bf16 hi/lo in MFMA B-fragment order ----
// t = ((h*4+kk)*8+nt)*64+lane ; writes whi[t*8..t*8+8)
__global__ __launch_bounds__(256) void prep_w3(
    const float* __restrict__ W3, short* __restrict__ whi,
    short* __restrict__ wlo)
{
    const int t    = blockIdx.x * 256 + threadIdx.x;   // 16384 threads
    const int lane = t & 63;
    const int nt   = (t >> 6) & 7;
    const int kk   = (t >> 9) & 3;
    const int h    = t >> 11;
    const int lm   = lane & 15;
    const int lg   = lane >> 4;

    const float* src = W3 + ((size_t)(h * NDIM + nt * 16 + lm)) * NDIM
                          + kk * 32 + lg * 8;
    const float4 a = *reinterpret_cast<const float4*>(src);
    const float4 b = *reinterpret_cast<const float4*>(src + 4);
    float xf[8] = {a.x, a.y, a.z, a.w, b.x, b.y, b.z, b.w};
    bf16x8 hi, lo;
#pragma unroll
    for (int j = 0; j < 8; ++j) {
        const unsigned u = __float_as_uint(xf[j]);
        hi[j] = (short)(u >> 16);
        const float hf = __uint_as_float(u & 0xffff0000u);
        lo[j] = (short)(__float_as_uint(xf[j] - hf) >> 16);
    }
    reinterpret_cast<bf16x8*>(whi)[t] = hi;
    reinterpret_cast<bf16x8*>(wlo)[t] = lo;
}

// ---- main: head=bid&7, 4 waves, runtime it-loop, 2 m-tiles per it ----
__global__ __launch_bounds__(256, 2) void bilinear_mfma(
    const float* __restrict__ x1, const float* __restrict__ x2,
    const float* __restrict__ W1, const float* __restrict__ W2,
    const short* __restrict__ whi, const short* __restrict__ wlo,
    float* __restrict__ psum, int itCount)
{
    const int tid = threadIdx.x;
    const int w   = tid >> 6;
    const int l   = tid & 63;
    const int lm  = l & 15;
    const int lg  = l >> 4;
    const int bid = blockIdx.x;
    const int h   = bid & 7;               // head pinned per-XCD (round-robin)
    const int wb  = (bid >> 3) * 256 + w * 64;   // wave's 64 samples

    __shared__ short lhi[4][4096];         // 32 KB: all 4 kk slabs, frag order
    __shared__ short llo[4][4096];         // 32 KB

    const short* __restrict__ shi = whi + (size_t)h * 16384;
    const short* __restrict__ slo = wlo + (size_t)h * 16384;
    const float* __restrict__ w1base = W1 + h * NDIM;

    // ---- stage the whole 64 KB once (zero staging VGPRs) ----
#pragma unroll
    for (int i = 0; i < 8; ++i) {
        gload_lds16(shi + (size_t)(i * 256 + tid) * 8,
                    &lhi[0][0] + (size_t)(i * 256 + w * 64) * 8);
        gload_lds16(slo + (size_t)(i * 256 + tid) * 8,
                    &llo[0][0] + (size_t)(i * 256 + w * 64) * 8);
    }

    float w2v[8];
#pragma unroll
    for (int nt = 0; nt < 8; ++nt) w2v[nt] = W2[h * NDIM + nt * 16 + lm];

    __syncthreads();   // drains vmcnt; the ONLY barrier in this kernel

    // barrier-free epilogue helper (numerics verified since R6)
    auto epi = [&](const f32x4 (&acc)[8], int bw, float t1v) {
        float cr[4];
        const float* x2base = x2 + (size_t)(bw + lg * 4) * (NHEAD * NDIM)
                                 + h * NDIM + lm;
#pragma unroll
        for (int r = 0; r < 4; ++r) {
            float s = 0.f;
#pragma unroll
            for (int nt = 0; nt < 8; ++nt)
                s += (acc[nt][r] + w2v[nt]) * x2base[(size_t)r * (NHEAD * NDIM) + nt * 16];
            cr[r] = s;
        }
#pragma unroll
        for (int m = 1; m < 16; m <<= 1)
#pragma unroll
            for (int r = 0; r < 4; ++r) cr[r] += __shfl_xor(cr[r], m, 64);
        float tf = t1v;
        tf += __shfl_xor(tf, 16, 64);
        tf += __shfl_xor(tf, 32, 64);
#pragma unroll
        for (int r = 0; r < 4; ++r) cr[r] += __shfl(tf, lg * 4 + r, 64);
        if (lm == 0) {
            float4 st;
            st.x = cr[0]; st.y = cr[1]; st.z = cr[2]; st.w = cr[3];
            *reinterpret_cast<float4*>(&psum[(size_t)h * NB + bw + lg * 4]) = st;
        }
    };

    for (int it = 0; it < itCount; ++it) {   // runtime bound -> no unroll
        const int bw0 = wb + it * 32;        // tile0 rows; tile1 = +16

        const float* x1b0 = x1 + (size_t)(bw0 + lm) * (NHEAD * NDIM)
                               + h * NDIM + lg * 8;
        const float* x1b1 = x1b0 + (size_t)16 * (NHEAD * NDIM);

        float4 pa0 = *reinterpret_cast<const float4*>(x1b0);
        float4 pb0 = *reinterpret_cast<const float4*>(x1b0 + 4);
        float4 pa1 = *reinterpret_cast<const float4*>(x1b1);
        float4 pb1 = *reinterpret_cast<const float4*>(x1b1 + 4);

        f32x4 acc0[8], acc1[8];
#pragma unroll
        for (int nt = 0; nt < 8; ++nt) { acc0[nt] = (f32x4)0.f; acc1[nt] = (f32x4)0.f; }
        float t1a = 0.f, t1b = 0.f;

#pragma unroll
        for (int kk = 0; kk < 4; ++kk) {
            const float4 ca0 = pa0, cb0 = pb0, ca1 = pa1, cb1 = pb1;
            if (kk < 3) {   // rolling x1 prefetch one kk ahead, both tiles
                pa0 = *reinterpret_cast<const float4*>(x1b0 + (kk + 1) * 32);
                pb0 = *reinterpret_cast<const float4*>(x1b0 + (kk + 1) * 32 + 4);
                pa1 = *reinterpret_cast<const float4*>(x1b1 + (kk + 1) * 32);
                pb1 = *reinterpret_cast<const float4*>(x1b1 + (kk + 1) * 32 + 4);
            }

            // A-fragment splits + t1 partials (exact fp32)
            bf16x8 a0hi, a0lo, a1hi, a1lo;
            {
                const int k0 = kk * 32 + lg * 8;
                const float4 wa = *reinterpret_cast<const float4*>(w1base + k0);
                const float4 wb4 = *reinterpret_cast<const float4*>(w1base + k0 + 4);
                float w1f[8] = {wa.x, wa.y, wa.z, wa.w, wb4.x, wb4.y, wb4.z, wb4.w};
                float xf0[8] = {ca0.x, ca0.y, ca0.z, ca0.w, cb0.x, cb0.y, cb0.z, cb0.w};
                float xf1[8] = {ca1.x, ca1.y, ca1.z, ca1.w, cb1.x, cb1.y, cb1.z, cb1.w};
#pragma unroll
                for (int j = 0; j < 8; ++j) {
                    unsigned u0 = __float_as_uint(xf0[j]);
                    a0hi[j] = (short)(u0 >> 16);
                    a0lo[j] = (short)(__float_as_uint(
                        xf0[j] - __uint_as_float(u0 & 0xffff0000u)) >> 16);
                    t1a += xf0[j] * w1f[j];
                    unsigned u1 = __float_as_uint(xf1[j]);
                    a1hi[j] = (short)(u1 >> 16);
                    a1lo[j] = (short)(__float_as_uint(
                        xf1[j] - __uint_as_float(u1 & 0xffff0000u)) >> 16);
                    t1b += xf1[j] * w1f[j];
                }
            }

            // B-fragments read ONCE, feed 6 MFMAs (2 tiles x 3 passes)
#pragma unroll
            for (int nt = 0; nt < 8; ++nt) {
                const bf16x8 bhi = *reinterpret_cast<const bf16x8*>(
                    &lhi[kk][nt * 512 + l * 8]);
                const bf16x8 blo = *reinterpret_cast<const bf16x8*>(
                    &llo[kk][nt * 512 + l * 8]);
                acc0[nt] = __builtin_amdgcn_mfma_f32_16x16x32_bf16(a0hi, bhi, acc0[nt], 0, 0, 0);
                acc1[nt] = __builtin_amdgcn_mfma_f32_16x16x32_bf16(a1hi, bhi, acc1[nt], 0, 0, 0);
                acc0[nt] = __builtin_amdgcn_mfma_f32_16x16x32_bf16(a0lo, bhi, acc0[nt], 0, 0, 0);
                acc1[nt] = __builtin_amdgcn_mfma_f32_16x16x32_bf16(a1lo, bhi, acc1[nt], 0, 0, 0);
                acc0[nt] = __builtin_amdgcn_mfma_f32_16x16x32_bf16(a0hi, blo, acc0[nt], 0, 0, 0);
                acc1[nt] = __builtin_amdgcn_mfma_f32_16x16x32_bf16(a1hi, blo, acc1[nt], 0, 0, 0);
            }
        }

        epi(acc0, bw0, t1a);
        epi(acc1, bw0 + 16, t1b);
    }
}

__global__ __launch_bounds__(256) void bilinear_reduce(
    const float* __restrict__ psum, const float* __restrict__ b1,
    float* __restrict__ out)
{
    const int i = blockIdx.x * 256 + threadIdx.x;
    float bs = 0.f;
#pragma unroll
    for (int hh = 0; hh < NHEAD; ++hh) bs += b1[hh];
    float s = bs;
#pragma unroll
    for (int hh = 0; hh < NHEAD; ++hh) s += psum[(size_t)hh * NB + i];
    out[i] = s;
}

extern "C" void kernel_launch(void* const* d_in, const int* in_sizes, int n_in,
                              void* d_out, int out_size, void* d_ws, size_t ws_size,
                              hipStream_t stream) {
    const float* x1 = (const float*)d_in[0];
    const float* x2 = (const float*)d_in[1];
    const float* W1 = (const float*)d_in[2];
    const float* b1 = (const float*)d_in[3];
    const float* W2 = (const float*)d_in[4];
    const float* W3 = (const float*)d_in[5];
    float* out = (float*)d_out;

    short* whi = (short*)d_ws;                          // 256 KB
    short* wlo = whi + (size_t)NHEAD * NDIM * NDIM;     // 256 KB
    float* psum = (float*)((char*)d_ws + 512 * 1024);   // 512 KB

    prep_w3<<<dim3(64), dim3(256), 0, stream>>>(W3, whi, wlo);
    // 512 blocks = 2/CU (one generation); each block: 4 waves x 2 its x 2 tiles
    bilinear_mfma<<<dim3(NB / 256 * NHEAD), dim3(256), 0, stream>>>(
        x1, x2, W1, W2, whi, wlo, psum, 2);
    bilinear_reduce<<<dim3(NB / 256), dim3(256), 0, stream>>>(psum, b1, out);
}

// Round 12
// 50.385 us; speedup vs baseline: 1.9151x; 1.8674x over previous
//
#include <hip/hip_runtime.h>

// out[b] = sum_h [ dot(x1_bh,W1_h) + b1_h + dot(x2_bh,W2_h)
//                  + sum_o x2_bh[o] * dot(W3_h[o,:], x1_bh) ]
// B=16384, HEAD=8, DIM=128.
//
// R12 = R11 minus the lambda (suspected spill source: acc arrays passed
// by-reference to a lambda become addressable -> scratch). Epilogue is
// manually inlined twice. Plain __launch_bounds__(256) (no min-waves) so
// the allocator never hits the 128-reg cliff.
// Rationale (R11 post-mortem): LDS pipe was the hidden bound (~10 us/CU at
// 4KB/sample ds_read_b128 traffic); 2 m-tiles per B-read halves it.
//  - Stage all 64 KB of W3_h once per block (gload_lds16), ONE barrier,
//    runtime-bound it-loop (no unroll), barrier-free main loop + epilogue.
//  - Grid 512 = 2 blocks/CU (LDS-capped); head=bid&7 XCD-pins W3 in L2.
//  - Numerics unchanged (proven R5-R11): split-bf16 3-pass, fragment-ordered
//    pre-split W3, shuffle epilogue, psum + reduce kernel.
// Fragment layouts (verified m89/m91): A: m=lane&15, k=(lane>>4)*8+j;
//   B: n=lane&15, same k; C/D: col=lane&15, row=(lane>>4)*4+reg.
// ws: [0,256K) whi | [256K,512K) wlo | [512K,1M) psum float[8][16384]

#define NB 16384
#define NHEAD 8
#define NDIM 128

typedef __attribute__((ext_vector_type(8))) short bf16x8;
typedef __attribute__((ext_vector_type(4))) float f32x4;

__device__ __forceinline__ void gload_lds16(const void* g, void* l) {
    __builtin_amdgcn_global_load_lds(
        (const __attribute__((address_space(1))) unsigned*)g,
        (__attribute__((address_space(3))) unsigned*)l, 16, 0, 0);
}

// ---- prep: split W3 into bf16 hi/lo in MFMA B-fragment order ----
// t = ((h*4+kk)*8+nt)*64+lane ; writes whi[t*8..t*8+8)
__global__ __launch_bounds__(256) void prep_w3(
    const float* __restrict__ W3, short* __restrict__ whi,
    short* __restrict__ wlo)
{
    const int t    = blockIdx.x * 256 + threadIdx.x;   // 16384 threads
    const int lane = t & 63;
    const int nt   = (t >> 6) & 7;
    const int kk   = (t >> 9) & 3;
    const int h    = t >> 11;
    const int lm   = lane & 15;
    const int lg   = lane >> 4;

    const float* src = W3 + ((size_t)(h * NDIM + nt * 16 + lm)) * NDIM
                          + kk * 32 + lg * 8;
    const float4 a = *reinterpret_cast<const float4*>(src);
    const float4 b = *reinterpret_cast<const float4*>(src + 4);
    float xf[8] = {a.x, a.y, a.z, a.w, b.x, b.y, b.z, b.w};
    bf16x8 hi, lo;
#pragma unroll
    for (int j = 0; j < 8; ++j) {
        const unsigned u = __float_as_uint(xf[j]);
        hi[j] = (short)(u >> 16);
        const float hf = __uint_as_float(u & 0xffff0000u);
        lo[j] = (short)(__float_as_uint(xf[j] - hf) >> 16);
    }
    reinterpret_cast<bf16x8*>(whi)[t] = hi;
    reinterpret_cast<bf16x8*>(wlo)[t] = lo;
}

// epilogue for one 16-sample tile: macro (NOT a lambda -> no array refs)
#define EPILOGUE(ACC, BW, T1V)                                               \
    {                                                                        \
        float cr[4];                                                         \
        const float* x2base = x2 + (size_t)((BW) + lg * 4) * (NHEAD * NDIM)  \
                                 + h * NDIM + lm;                            \
        _Pragma("unroll")                                                    \
        for (int r = 0; r < 4; ++r) {                                        \
            float s = 0.f;                                                   \
            _Pragma("unroll")                                                \
            for (int nt = 0; nt < 8; ++nt)                                   \
                s += (ACC[nt][r] + w2v[nt])                                  \
                   * x2base[(size_t)r * (NHEAD * NDIM) + nt * 16];           \
            cr[r] = s;                                                       \
        }                                                                    \
        _Pragma("unroll")                                                    \
        for (int m = 1; m < 16; m <<= 1) {                                   \
            _Pragma("unroll")                                                \
            for (int r = 0; r < 4; ++r) cr[r] += __shfl_xor(cr[r], m, 64);   \
        }                                                                    \
        float tf = (T1V);                                                    \
        tf += __shfl_xor(tf, 16, 64);                                        \
        tf += __shfl_xor(tf, 32, 64);                                        \
        _Pragma("unroll")                                                    \
        for (int r = 0; r < 4; ++r) cr[r] += __shfl(tf, lg * 4 + r, 64);     \
        if (lm == 0) {                                                       \
            float4 st;                                                       \
            st.x = cr[0]; st.y = cr[1]; st.z = cr[2]; st.w = cr[3];          \
            *reinterpret_cast<float4*>(                                      \
                &psum[(size_t)h * NB + (BW) + lg * 4]) = st;                 \
        }                                                                    \
    }

// ---- main: head=bid&7, 4 waves, runtime it-loop, 2 m-tiles per it ----
__global__ __launch_bounds__(256) void bilinear_mfma(
    const float* __restrict__ x1, const float* __restrict__ x2,
    const float* __restrict__ W1, const float* __restrict__ W2,
    const short* __restrict__ whi, const short* __restrict__ wlo,
    float* __restrict__ psum, int itCount)
{
    const int tid = threadIdx.x;
    const int w   = tid >> 6;
    const int l   = tid & 63;
    const int lm  = l & 15;
    const int lg  = l >> 4;
    const int bid = blockIdx.x;
    const int h   = bid & 7;               // head pinned per-XCD (round-robin)
    const int wb  = (bid >> 3) * 256 + w * 64;   // wave's 64 samples

    __shared__ short lhi[4][4096];         // 32 KB: all 4 kk slabs, frag order
    __shared__ short llo[4][4096];         // 32 KB

    const short* __restrict__ shi = whi + (size_t)h * 16384;
    const short* __restrict__ slo = wlo + (size_t)h * 16384;
    const float* __restrict__ w1base = W1 + h * NDIM;

    // ---- stage the whole 64 KB once (zero staging VGPRs) ----
#pragma unroll
    for (int i = 0; i < 8; ++i) {
        gload_lds16(shi + (size_t)(i * 256 + tid) * 8,
                    &lhi[0][0] + (size_t)(i * 256 + w * 64) * 8);
        gload_lds16(slo + (size_t)(i * 256 + tid) * 8,
                    &llo[0][0] + (size_t)(i * 256 + w * 64) * 8);
    }

    float w2v[8];
#pragma unroll
    for (int nt = 0; nt < 8; ++nt) w2v[nt] = W2[h * NDIM + nt * 16 + lm];

    __syncthreads();   // drains vmcnt; the ONLY barrier in this kernel

    for (int it = 0; it < itCount; ++it) {   // runtime bound -> no unroll
        const int bw0 = wb + it * 32;        // tile0 rows; tile1 = +16

        const float* x1b0 = x1 + (size_t)(bw0 + lm) * (NHEAD * NDIM)
                               + h * NDIM + lg * 8;
        const float* x1b1 = x1b0 + (size_t)16 * (NHEAD * NDIM);

        float4 pa0 = *reinterpret_cast<const float4*>(x1b0);
        float4 pb0 = *reinterpret_cast<const float4*>(x1b0 + 4);
        float4 pa1 = *reinterpret_cast<const float4*>(x1b1);
        float4 pb1 = *reinterpret_cast<const float4*>(x1b1 + 4);

        f32x4 acc0[8], acc1[8];
#pragma unroll
        for (int nt = 0; nt < 8; ++nt) { acc0[nt] = (f32x4)0.f; acc1[nt] = (f32x4)0.f; }
        float t1a = 0.f, t1b = 0.f;

#pragma unroll
        for (int kk = 0; kk < 4; ++kk) {
            const float4 ca0 = pa0, cb0 = pb0, ca1 = pa1, cb1 = pb1;
            if (kk < 3) {   // rolling x1 prefetch one kk ahead, both tiles
                pa0 = *reinterpret_cast<const float4*>(x1b0 + (kk + 1) * 32);
                pb0 = *reinterpret_cast<const float4*>(x1b0 + (kk + 1) * 32 + 4);
                pa1 = *reinterpret_cast<const float4*>(x1b1 + (kk + 1) * 32);
                pb1 = *reinterpret_cast<const float4*>(x1b1 + (kk + 1) * 32 + 4);
            }

            // A-fragment splits + t1 partials (exact fp32)
            bf16x8 a0hi, a0lo, a1hi, a1lo;
            {
                const int k0 = kk * 32 + lg * 8;
                const float4 wa = *reinterpret_cast<const float4*>(w1base + k0);
                const float4 wb4 = *reinterpret_cast<const float4*>(w1base + k0 + 4);
                float w1f[8] = {wa.x, wa.y, wa.z, wa.w, wb4.x, wb4.y, wb4.z, wb4.w};
                float xf0[8] = {ca0.x, ca0.y, ca0.z, ca0.w, cb0.x, cb0.y, cb0.z, cb0.w};
                float xf1[8] = {ca1.x, ca1.y, ca1.z, ca1.w, cb1.x, cb1.y, cb1.z, cb1.w};
#pragma unroll
                for (int j = 0; j < 8; ++j) {
                    unsigned u0 = __float_as_uint(xf0[j]);
                    a0hi[j] = (short)(u0 >> 16);
                    a0lo[j] = (short)(__float_as_uint(
                        xf0[j] - __uint_as_float(u0 & 0xffff0000u)) >> 16);
                    t1a += xf0[j] * w1f[j];
                    unsigned u1 = __float_as_uint(xf1[j]);
                    a1hi[j] = (short)(u1 >> 16);
                    a1lo[j] = (short)(__float_as_uint(
                        xf1[j] - __uint_as_float(u1 & 0xffff0000u)) >> 16);
                    t1b += xf1[j] * w1f[j];
                }
            }

            // B-fragments read ONCE, feed 6 MFMAs (2 tiles x 3 passes)
#pragma unroll
            for (int nt = 0; nt < 8; ++nt) {
                const bf16x8 bhi = *reinterpret_cast<const bf16x8*>(
                    &lhi[kk][nt * 512 + l * 8]);
                const bf16x8 blo = *reinterpret_cast<const bf16x8*>(
                    &llo[kk][nt * 512 + l * 8]);
                acc0[nt] = __builtin_amdgcn_mfma_f32_16x16x32_bf16(a0hi, bhi, acc0[nt], 0, 0, 0);
                acc1[nt] = __builtin_amdgcn_mfma_f32_16x16x32_bf16(a1hi, bhi, acc1[nt], 0, 0, 0);
                acc0[nt] = __builtin_amdgcn_mfma_f32_16x16x32_bf16(a0lo, bhi, acc0[nt], 0, 0, 0);
                acc1[nt] = __builtin_amdgcn_mfma_f32_16x16x32_bf16(a1lo, bhi, acc1[nt], 0, 0, 0);
                acc0[nt] = __builtin_amdgcn_mfma_f32_16x16x32_bf16(a0hi, blo, acc0[nt], 0, 0, 0);
                acc1[nt] = __builtin_amdgcn_mfma_f32_16x16x32_bf16(a1hi, blo, acc1[nt], 0, 0, 0);
            }
        }

        EPILOGUE(acc0, bw0, t1a)
        EPILOGUE(acc1, bw0 + 16, t1b)
    }
}

__global__ __launch_bounds__(256) void bilinear_reduce(
    const float* __restrict__ psum, const float* __restrict__ b1,
    float* __restrict__ out)
{
    const int i = blockIdx.x * 256 + threadIdx.x;
    float bs = 0.f;
#pragma unroll
    for (int hh = 0; hh < NHEAD; ++hh) bs += b1[hh];
    float s = bs;
#pragma unroll
    for (int hh = 0; hh < NHEAD; ++hh) s += psum[(size_t)hh * NB + i];
    out[i] = s;
}

extern "C" void kernel_launch(void* const* d_in, const int* in_sizes, int n_in,
                              void* d_out, int out_size, void* d_ws, size_t ws_size,
                              hipStream_t stream) {
    const float* x1 = (const float*)d_in[0];
    const float* x2 = (const float*)d_in[1];
    const float* W1 = (const float*)d_in[2];
    const float* b1 = (const float*)d_in[3];
    const float* W2 = (const float*)d_in[4];
    const float* W3 = (const float*)d_in[5];
    float* out = (float*)d_out;

    short* whi = (short*)d_ws;                          // 256 KB
    short* wlo = whi + (size_t)NHEAD * NDIM * NDIM;     // 256 KB
    float* psum = (float*)((char*)d_ws + 512 * 1024);   // 512 KB

    prep_w3<<<dim3(64), dim3(256), 0, stream>>>(W3, whi, wlo);
    // 512 blocks = 2/CU; each block: 4 waves x 2 its x 2 tiles = 256 samples
    bilinear_mfma<<<dim3(NB / 256 * NHEAD), dim3(256), 0, stream>>>(
        x1, x2, W1, W2, whi, wlo, psum, 2);
    bilinear_reduce<<<dim3(NB / 256), dim3(256), 0, stream>>>(psum, b1, out);
}

// Round 13
// 37.639 us; speedup vs baseline: 2.5637x; 1.3387x over previous
//
#include <hip/hip_runtime.h>

// out[b] = sum_h [ dot(x1_bh,W1_h) + b1_h + dot(x2_bh,W2_h)
//                  + sum_o x2_bh[o] * dot(W3_h[o,:], x1_bh) ]
// B=16384, HEAD=8, DIM=128.
//
// R13: switch to mfma_f32_32x32x16_bf16. A 32-sample tile shares each
// B-fragment read across 32 samples (2 KB LDS-read per sample, half of the
// 16x16 single-tile scheme) with ONE acc[4] f32x16 = 64 AGPR (vs 128 for the
// equivalent 16x16 2-tile interleave). Total ~120 unified regs -> 4 waves/EU.
//  - Block 256 thr = 4 waves x 32 samples = 128 samples; grid 1024
//    (= NB/128 x 8 heads) = 4 blocks/CU, ONE co-resident generation,
//    16 waves/CU. head = bid&7 -> all blocks on an XCD share one head's W3.
//  - LDS 32 KB: one phase = 4 k-steps (16+16 KB hi/lo); 2 phases, staged via
//    gload_lds16 (zero staging regs), 3 barriers total.
//  - W1 folded with uniform scalar loads + cndmask (no VGPR array);
//    split-bf16 3-pass numerics unchanged (hi*hi + lo*hi + hi*lo).
//  - Epilogue: per-lane 64 x2 dwords (fully coalesced per 32-lane group),
//    5-level shfl_xor column reduction, t1 via shfl fold, static-select
//    writer (no runtime-indexed arrays -> no scratch).
// Layouts (m74/m101 HW-verified C/D; A/B natural mapping, k-map errors
// cancel by A/B symmetry):
//   A: m=lane&31, k=(lane>>5)*8+j   B: n=lane&31, same k (B[k][n]=W3[n][k])
//   C/D: col=lane&31, row=(reg&3)+8*(reg>>2)+4*(lane>>5), reg in [0,16)
// ws: [0,256K) whi | [256K,512K) wlo | [512K,1M) psum float[8][16384]

#define NB 16384
#define NHEAD 8
#define NDIM 128

typedef __attribute__((ext_vector_type(8))) short bf16x8;
typedef __attribute__((ext_vector_type(16))) float f32x16;

__device__ __forceinline__ void gload_lds16(const void* g, void* l) {
    __builtin_amdgcn_global_load_lds(
        (const __attribute__((address_space(1))) unsigned*)g,
        (__attribute__((address_space(3))) unsigned*)l, 16, 0, 0);
}

// ---- prep: split W3 into bf16 hi/lo in 32x32x16 B-fragment order ----
// t = ((h*8+ks)*4+nt)*64+lane ; writes whi[t*8..t*8+8)
// B-frag elem j of lane: n = nt*32+(lane&31), k = ks*16+(lane>>5)*8+j
__global__ __launch_bounds__(256) void prep_w3(
    const float* __restrict__ W3, short* __restrict__ whi,
    short* __restrict__ wlo)
{
    const int t    = blockIdx.x * 256 + threadIdx.x;   // 16384 threads
    const int lane = t & 63;
    const int nt   = (t >> 6) & 3;
    const int ks   = (t >> 8) & 7;
    const int h    = t >> 11;
    const int n    = nt * 32 + (lane & 31);
    const int k    = ks * 16 + (lane >> 5) * 8;

    const float* src = W3 + ((size_t)(h * NDIM + n)) * NDIM + k;
    const float4 a = *reinterpret_cast<const float4*>(src);
    const float4 b = *reinterpret_cast<const float4*>(src + 4);
    float xf[8] = {a.x, a.y, a.z, a.w, b.x, b.y, b.z, b.w};
    bf16x8 hi, lo;
#pragma unroll
    for (int j = 0; j < 8; ++j) {
        const unsigned u = __float_as_uint(xf[j]);
        hi[j] = (short)(u >> 16);
        const float hf = __uint_as_float(u & 0xffff0000u);
        lo[j] = (short)(__float_as_uint(xf[j] - hf) >> 16);
    }
    reinterpret_cast<bf16x8*>(whi)[t] = hi;
    reinterpret_cast<bf16x8*>(wlo)[t] = lo;
}

// ---- main: head=bid&7, 4 waves x 32 samples = 128 samples/block ----
__global__ __launch_bounds__(256, 4) void bilinear_mfma(
    const float* __restrict__ x1, const float* __restrict__ x2,
    const float* __restrict__ W1, const float* __restrict__ W2,
    const short* __restrict__ whi, const short* __restrict__ wlo,
    float* __restrict__ psum)
{
    const int tid  = threadIdx.x;
    const int w    = tid >> 6;
    const int l    = tid & 63;
    const int col  = l & 31;     // A-row m / B,C-col n / sample-in-tile
    const int hi5  = l >> 5;     // k-half; C-row group
    const int bid  = blockIdx.x;
    const int h    = bid & 7;    // head pinned per-XCD (round-robin)
    const int bw   = (bid >> 3) * 128 + w * 32;   // wave's 32 samples

    __shared__ short lhi[4][4][512];   // 16 KB: one phase (4 ksteps), frag order
    __shared__ short llo[4][4][512];   // 16 KB

    const short* __restrict__ shi = whi + (size_t)h * 16384;
    const short* __restrict__ slo = wlo + (size_t)h * 16384;
    const float* __restrict__ w1base = W1 + h * NDIM;
    const float* __restrict__ x1row  = x1 + (size_t)(bw + col) * (NHEAD * NDIM)
                                          + h * NDIM + hi5 * 8;

    f32x16 acc[4];
#pragma unroll
    for (int nt = 0; nt < 4; ++nt) acc[nt] = (f32x16)0.f;
    float t1 = 0.f;

    for (int p = 0; p < 2; ++p) {
        // ---- stage phase p: ksteps 4p..4p+3, 16+16 KB via gload_lds16 ----
#pragma unroll
        for (int i = 0; i < 4; ++i) {
            gload_lds16(shi + (size_t)(p * 1024 + i * 256 + tid) * 8,
                        &lhi[0][0][0] + (size_t)(i * 256 + w * 64) * 8);
            gload_lds16(slo + (size_t)(p * 1024 + i * 256 + tid) * 8,
                        &llo[0][0][0] + (size_t)(i * 256 + w * 64) * 8);
        }
        __syncthreads();   // drains vmcnt -> phase slab ready

#pragma unroll
        for (int ks = 0; ks < 4; ++ks) {
            const int kbase = p * 64 + ks * 16;   // lane adds hi5*8 via x1row

            // A-fragment: 8 floats of x1, split in-register; t1 partial
            bf16x8 ahi, alo;
            {
                const float4 a = *reinterpret_cast<const float4*>(x1row + kbase);
                const float4 b = *reinterpret_cast<const float4*>(x1row + kbase + 4);
                float xf[8] = {a.x, a.y, a.z, a.w, b.x, b.y, b.z, b.w};
#pragma unroll
                for (int j = 0; j < 8; ++j) {
                    // W1: two uniform 8-float halves (scalar loads), select by hi5
                    const float w1l = w1base[kbase + j];
                    const float w1h = w1base[kbase + 8 + j];
                    const unsigned u = __float_as_uint(xf[j]);
                    ahi[j] = (short)(u >> 16);
                    alo[j] = (short)(__float_as_uint(
                        xf[j] - __uint_as_float(u & 0xffff0000u)) >> 16);
                    t1 += xf[j] * (hi5 ? w1h : w1l);
                }
            }

            // B-fragments from LDS (stride-1 b128, conflict-free), 3-pass
#pragma unroll
            for (int nt = 0; nt < 4; ++nt) {
                const bf16x8 bhi = *reinterpret_cast<const bf16x8*>(&lhi[ks][nt][l * 8]);
                const bf16x8 blo = *reinterpret_cast<const bf16x8*>(&llo[ks][nt][l * 8]);
                acc[nt] = __builtin_amdgcn_mfma_f32_32x32x16_bf16(ahi, bhi, acc[nt], 0, 0, 0);
                acc[nt] = __builtin_amdgcn_mfma_f32_32x32x16_bf16(alo, bhi, acc[nt], 0, 0, 0);
                acc[nt] = __builtin_amdgcn_mfma_f32_32x32x16_bf16(ahi, blo, acc[nt], 0, 0, 0);
            }
        }
        if (p == 0) __syncthreads();   // reads done before restage
    }

    // ---- epilogue: cr[reg] = sum_o (P[row,o]+W2[o])*x2[row,o] ----
    float w2v[4];
#pragma unroll
    for (int nt = 0; nt < 4; ++nt) w2v[nt] = W2[h * NDIM + nt * 32 + col];

    float cr[16];
#pragma unroll
    for (int reg = 0; reg < 16; ++reg) {
        const int row = (reg & 3) + 8 * (reg >> 2) + 4 * hi5;
        const float* x2p = x2 + (size_t)(bw + row) * (NHEAD * NDIM)
                              + h * NDIM + col;
        float s = 0.f;
#pragma unroll
        for (int nt = 0; nt < 4; ++nt)
            s += (acc[nt][reg] + w2v[nt]) * x2p[nt * 32];
        cr[reg] = s;
    }
    // reduce the 32 column-partials within each 32-lane half-group
#pragma unroll
    for (int m = 1; m < 32; m <<= 1)
#pragma unroll
        for (int reg = 0; reg < 16; ++reg)
            cr[reg] += __shfl_xor(cr[reg], m, 64);

    // t1: lane holds half-row dot for sample col; fold halves -> full t1
    float tf = t1;
    tf += __shfl_xor(tf, 32, 64);
#pragma unroll
    for (int reg = 0; reg < 16; ++reg) {
        const int row = (reg & 3) + 8 * (reg >> 2) + 4 * hi5;
        cr[reg] += __shfl(tf, row, 64);   // lane 'row' (<32) has t1[row]
    }

    // writer: lanes col<16 write reg=col's value (static select, rule #20)
    float outv = cr[0];
#pragma unroll
    for (int reg = 1; reg < 16; ++reg)
        if (col == reg) outv = cr[reg];
    if (col < 16) {
        const int row = (col & 3) + 8 * (col >> 2) + 4 * hi5;
        psum[(size_t)h * NB + bw + row] = outv;
    }
}

__global__ __launch_bounds__(256) void bilinear_reduce(
    const float* __restrict__ psum, const float* __restrict__ b1,
    float* __restrict__ out)
{
    const int i = blockIdx.x * 256 + threadIdx.x;
    float bs = 0.f;
#pragma unroll
    for (int hh = 0; hh < NHEAD; ++hh) bs += b1[hh];
    float s = bs;
#pragma unroll
    for (int hh = 0; hh < NHEAD; ++hh) s += psum[(size_t)hh * NB + i];
    out[i] = s;
}

extern "C" void kernel_launch(void* const* d_in, const int* in_sizes, int n_in,
                              void* d_out, int out_size, void* d_ws, size_t ws_size,
                              hipStream_t stream) {
    const float* x1 = (const float*)d_in[0];
    const float* x2 = (const float*)d_in[1];
    const float* W1 = (const float*)d_in[2];
    const float* b1 = (const float*)d_in[3];
    const float* W2 = (const float*)d_in[4];
    const float* W3 = (const float*)d_in[5];
    float* out = (float*)d_out;

    short* whi = (short*)d_ws;                          // 256 KB
    short* wlo = whi + (size_t)NHEAD * NDIM * NDIM;     // 256 KB
    float* psum = (float*)((char*)d_ws + 512 * 1024);   // 512 KB

    prep_w3<<<dim3(64), dim3(256), 0, stream>>>(W3, whi, wlo);
    // 1024 blocks = 4/CU (one generation); 4 waves x 32 samples each
    bilinear_mfma<<<dim3(NB / 128 * NHEAD), dim3(256), 0, stream>>>(
        x1, x2, W1, W2, whi, wlo, psum);
    bilinear_reduce<<<dim3(NB / 256), dim3(256), 0, stream>>>(psum, b1, out);
}